// Round 1
// baseline (784.852 us; speedup 1.0000x reference)
//
#include <hip/hip_runtime.h>
#include <stdint.h>

// Problem constants
#define M_ROWS 256
#define K_DIM  2048
#define N_FEAT 65536
#define P_PROTO 4096
#define INV_T  20.0f      // 1/0.05
#define N_CLS  69632.0f   // P + N

typedef __attribute__((ext_vector_type(8))) __bf16 bf16x8;
typedef __attribute__((ext_vector_type(4))) float  f32x4;

__device__ __forceinline__ unsigned short f2bf_rne(float f) {
    unsigned int u = __float_as_uint(f);
    u += 0x7fffu + ((u >> 16) & 1u);
    return (unsigned short)(u >> 16);
}

// ---------------------------------------------------------------------------
// Kernel 1: L2-normalize rows of inputs [256 x 2048] fp32 -> bf16 (bit-stored)
// one block per row, 256 threads, 8 floats/thread
// ---------------------------------------------------------------------------
__global__ __launch_bounds__(256) void prep_norm(const float* __restrict__ in,
                                                 unsigned short* __restrict__ xb) {
    const int row = blockIdx.x;
    const int tid = threadIdx.x;
    const float4* r = (const float4*)(in + (size_t)row * K_DIM);
    float4 v0 = r[tid];
    float4 v1 = r[tid + 256];
    float ss = v0.x*v0.x + v0.y*v0.y + v0.z*v0.z + v0.w*v0.w
             + v1.x*v1.x + v1.y*v1.y + v1.z*v1.z + v1.w*v1.w;
    #pragma unroll
    for (int off = 32; off; off >>= 1) ss += __shfl_down(ss, off, 64);
    __shared__ float wsum[4];
    if ((tid & 63) == 0) wsum[tid >> 6] = ss;
    __syncthreads();
    float scale = rsqrtf(wsum[0] + wsum[1] + wsum[2] + wsum[3]);

    ushort4 o0, o1;
    o0.x = f2bf_rne(v0.x * scale); o0.y = f2bf_rne(v0.y * scale);
    o0.z = f2bf_rne(v0.z * scale); o0.w = f2bf_rne(v0.w * scale);
    o1.x = f2bf_rne(v1.x * scale); o1.y = f2bf_rne(v1.y * scale);
    o1.z = f2bf_rne(v1.z * scale); o1.w = f2bf_rne(v1.w * scale);
    ushort4* o = (ushort4*)(xb + (size_t)row * K_DIM);
    o[tid]       = o0;
    o[tid + 256] = o1;
}

// ---------------------------------------------------------------------------
// Kernel 2: C[256, 65536] = Xbf16[256,2048] . F[65536,2048]^T
// Block tile: M=256 (full), N=64, BK=32. 256 threads = 4 waves.
// A staged via global_load_lds (16B), B staged fp32->bf16 convert on the fly.
// Each wave: 4 m-frags x 4 n-frags of mfma_f32_16x16x32_bf16.
// ---------------------------------------------------------------------------
#define BK 32
#define NT 64

__global__ __launch_bounds__(256) void gemm_nt(const unsigned short* __restrict__ xb,
                                               const float* __restrict__ feat,
                                               float* __restrict__ C) {
    __shared__ unsigned short lA[M_ROWS * BK];  // [m][k], 64B rows, 16 KB
    __shared__ unsigned short lB[NT * BK];      // [n][k], 64B rows, 4 KB

    const int tid = threadIdx.x;
    const int w   = tid >> 6;     // wave 0..3
    const int l   = tid & 63;     // lane
    const int lr  = l & 15;       // frag row/col index
    const int lq  = l >> 4;       // quad 0..3
    const int n0  = blockIdx.x * NT;

    // A staging source: wave w, inst t covers rows w*64 + t*16; lane l -> row +(l>>2), k-chunk (l&3)*8
    const unsigned short* agp = xb + (size_t)(w * 64 + (l >> 2)) * K_DIM + (l & 3) * 8;
    // B staging: thread -> feature row bn, k-chunk bc*8 (8 floats = 2 float4)
    const int bn = tid >> 2;      // 0..63
    const int bc = tid & 3;       // 0..3
    const float* fptr = feat + (size_t)(n0 + bn) * K_DIM + bc * 8;
    unsigned short* lbdst = lB + bn * BK + bc * 8;

    // compute-phase LDS pointers
    const unsigned short* aptr = lA + (size_t)((w * 4) * 16 + lr) * BK + lq * 8;
    const unsigned short* bptr = lB + (size_t)lr * BK + lq * 8;

    f32x4 acc[4][4];
    #pragma unroll
    for (int i = 0; i < 4; ++i)
        #pragma unroll
        for (int j = 0; j < 4; ++j)
            acc[i][j] = (f32x4){0.f, 0.f, 0.f, 0.f};

    for (int kt = 0; kt < K_DIM / BK; ++kt) {
        __syncthreads();
        // --- stage A via async global->LDS, 16B/lane, 4 insts/wave ---
        #pragma unroll
        for (int t = 0; t < 4; ++t) {
            __builtin_amdgcn_global_load_lds(
                (const __attribute__((address_space(1))) void*)(agp + (size_t)t * 16 * K_DIM),
                (__attribute__((address_space(3))) void*)((char*)lA + w * 4096 + t * 1024),
                16, 0, 0);
        }
        // --- stage B: load 8 fp32, convert RNE to bf16, one 16B LDS write ---
        float4 f0 = *(const float4*)(fptr);
        float4 f1 = *(const float4*)(fptr + 4);
        uint4 pk;
        pk.x = (unsigned)f2bf_rne(f0.x) | ((unsigned)f2bf_rne(f0.y) << 16);
        pk.y = (unsigned)f2bf_rne(f0.z) | ((unsigned)f2bf_rne(f0.w) << 16);
        pk.z = (unsigned)f2bf_rne(f1.x) | ((unsigned)f2bf_rne(f1.y) << 16);
        pk.w = (unsigned)f2bf_rne(f1.z) | ((unsigned)f2bf_rne(f1.w) << 16);
        *(uint4*)lbdst = pk;
        agp  += BK;
        fptr += BK;
        __syncthreads();

        // --- compute: 4 A frags, 4 B frags, 16 MFMAs ---
        bf16x8 a[4], b[4];
        #pragma unroll
        for (int i = 0; i < 4; ++i) a[i] = *(const bf16x8*)(aptr + (size_t)i * 16 * BK);
        #pragma unroll
        for (int j = 0; j < 4; ++j) b[j] = *(const bf16x8*)(bptr + (size_t)j * 16 * BK);
        #pragma unroll
        for (int i = 0; i < 4; ++i)
            #pragma unroll
            for (int j = 0; j < 4; ++j)
                acc[i][j] = __builtin_amdgcn_mfma_f32_16x16x32_bf16(a[i], b[j], acc[i][j], 0, 0, 0);
    }

    // --- epilogue: C/D layout col=lane&15, row=quad*4+reg ---
    #pragma unroll
    for (int i = 0; i < 4; ++i) {
        const int mbase = (w * 4 + i) * 16 + lq * 4;
        #pragma unroll
        for (int j = 0; j < 4; ++j) {
            const int col = n0 + j * 16 + lr;
            #pragma unroll
            for (int r = 0; r < 4; ++r)
                C[(size_t)(mbase + r) * N_FEAT + col] = acc[i][j][r];
        }
    }
}

// ---------------------------------------------------------------------------
// Kernel 3: per-row online logsumexp + sum(logits) + target logit
// logits row = [proto[row,:]*20 , C[row,:]*20], length 69632
// rowvals[row] = lse - 0.9*logit_t - 0.1*(sum/69632)
// ---------------------------------------------------------------------------
__device__ __forceinline__ void online_lse(float v, float& m, float& s) {
    if (v > m) { s = s * __expf(m - v) + 1.0f; m = v; }
    else       { s += __expf(v - m); }
}

__global__ __launch_bounds__(256) void row_reduce(const float* __restrict__ proto,
                                                  const float* __restrict__ C,
                                                  const int* __restrict__ targets,
                                                  float* __restrict__ rowvals) {
    const int row = blockIdx.x;
    const int tid = threadIdx.x;
    const float* p = proto + (size_t)row * P_PROTO;
    const float* c = C + (size_t)row * N_FEAT;

    float m = -1.0e30f, s = 0.0f, sum = 0.0f;

    const float4* p4 = (const float4*)p;
    for (int i = tid; i < P_PROTO / 4; i += 256) {
        float4 v = p4[i];
        float a0 = v.x * INV_T, a1 = v.y * INV_T, a2 = v.z * INV_T, a3 = v.w * INV_T;
        sum += a0 + a1 + a2 + a3;
        online_lse(a0, m, s); online_lse(a1, m, s);
        online_lse(a2, m, s); online_lse(a3, m, s);
    }
    const float4* c4 = (const float4*)c;
    for (int i = tid; i < N_FEAT / 4; i += 256) {
        float4 v = c4[i];
        float a0 = v.x * INV_T, a1 = v.y * INV_T, a2 = v.z * INV_T, a3 = v.w * INV_T;
        sum += a0 + a1 + a2 + a3;
        online_lse(a0, m, s); online_lse(a1, m, s);
        online_lse(a2, m, s); online_lse(a3, m, s);
    }

    __shared__ float rm[256], rs[256], rsum[256];
    rm[tid] = m; rs[tid] = s; rsum[tid] = sum;
    __syncthreads();
    #pragma unroll
    for (int off = 128; off; off >>= 1) {
        if (tid < off) {
            float m2 = rm[tid + off], s2 = rs[tid + off];
            float mn = fmaxf(rm[tid], m2);
            rs[tid] = rs[tid] * __expf(rm[tid] - mn) + s2 * __expf(m2 - mn);
            rm[tid] = mn;
            rsum[tid] += rsum[tid + off];
        }
        __syncthreads();
    }
    if (tid == 0) {
        const int t = targets[row];
        const float lt = c[t] * INV_T;
        const float lse = rm[0] + __logf(rs[0]);
        rowvals[row] = lse - 0.9f * lt - 0.1f * (rsum[0] / N_CLS);
    }
}

// ---------------------------------------------------------------------------
// Kernel 4: mean of 256 rowvals -> scalar loss
// ---------------------------------------------------------------------------
__global__ __launch_bounds__(256) void final_mean(const float* __restrict__ rowvals,
                                                  float* __restrict__ out) {
    const int tid = threadIdx.x;
    float v = rowvals[tid];
    #pragma unroll
    for (int off = 32; off; off >>= 1) v += __shfl_down(v, off, 64);
    __shared__ float ws[4];
    if ((tid & 63) == 0) ws[tid >> 6] = v;
    __syncthreads();
    if (tid == 0) out[0] = (ws[0] + ws[1] + ws[2] + ws[3]) * (1.0f / 256.0f);
}

// ---------------------------------------------------------------------------
extern "C" void kernel_launch(void* const* d_in, const int* in_sizes, int n_in,
                              void* d_out, int out_size, void* d_ws, size_t ws_size,
                              hipStream_t stream) {
    const float* inputs  = (const float*)d_in[0];
    const int*   targets = (const int*)d_in[1];
    const float* proto   = (const float*)d_in[2];
    const float* feat    = (const float*)d_in[3];

    // workspace layout
    unsigned short* xb = (unsigned short*)d_ws;                               // 1 MB
    float* C       = (float*)((char*)d_ws + (size_t)M_ROWS * K_DIM * 2);      // 64 MB
    float* rowvals = (float*)((char*)C + (size_t)M_ROWS * N_FEAT * 4);        // 1 KB
    float* out     = (float*)d_out;

    prep_norm <<<M_ROWS, 256, 0, stream>>>(inputs, xb);
    gemm_nt   <<<N_FEAT / NT, 256, 0, stream>>>(xb, feat, C);
    row_reduce<<<M_ROWS, 256, 0, stream>>>(proto, C, targets, rowvals);
    final_mean<<<1, 256, 0, stream>>>(rowvals, out);
}